// Round 1
// baseline (29.619 us; speedup 1.0000x reference)
//
#include <hip/hip_runtime.h>

// Problem constants (MultiScaleHead): B=16, L=2048, H=1024, P=16, S=128
#define B_ 16
#define L_ 2048
#define H_ 1024
#define P_ 16
#define S_ 128

// Kernel 1: compute per-(b,s) scalar weights w[b,s] and init out with bias.
// w[b,s] = sum_p valid[p] * sel[p,s] / (par_cnt * sent_cnt[p])
__global__ void msh_weights(const int* __restrict__ par_head,
                            const int* __restrict__ par_tail,
                            const int* __restrict__ sent_head,
                            const float* __restrict__ bias,
                            float* __restrict__ w_out,
                            float* __restrict__ out) {
    int b = blockIdx.x;
    int t = threadIdx.x;  // 0..127 (one per sentence)

    __shared__ int   sh[S_];
    __shared__ float inv_scnt[P_];   // valid[p] ? 1/sent_cnt[p] : 0
    __shared__ int   validp[P_];
    __shared__ float invpar;

    sh[t] = sent_head[b * S_ + t];
    __syncthreads();

    if (t < P_) {
        int head = par_head[b * P_ + t];
        int tail = par_tail[b * P_ + t];
        int cnt = 0, anynz = 0;
        for (int s = 0; s < S_; ++s) {
            int inside = (head <= sh[s]) && (sh[s] <= tail);
            cnt += inside;
            anynz |= (inside && (sh[s] != 0));
        }
        int valid = ((tail - head) > 2) && anynz;
        validp[t] = valid;
        inv_scnt[t] = valid ? (1.0f / (float)(cnt > 1 ? cnt : 1)) : 0.0f;
    }
    __syncthreads();

    if (t == 0) {
        int pc = 0;
        for (int p = 0; p < P_; ++p) pc += validp[p];
        invpar = 1.0f / (float)(pc > 1 ? pc : 1);
    }
    __syncthreads();

    int myh = sh[t];
    float w = 0.0f;
    for (int p = 0; p < P_; ++p) {
        int head = par_head[b * P_ + p];
        int tail = par_tail[b * P_ + p];
        if (head <= myh && myh <= tail) w += inv_scnt[p];
    }
    w_out[b * S_ + t] = w * invpar;

    // init output with bias (re-done every call; kernel 2 atomically adds)
    if (t < 5) out[b * 5 + t] = bias[t];
}

// Kernel 2: one block per (b,s). Gather emb row, 5 dot products vs W rows,
// block-reduce, atomicAdd weighted result into out.
__global__ void __launch_bounds__(256) msh_main(
        const float* __restrict__ backbone,
        const int* __restrict__ sent_head,
        const float* __restrict__ W,
        const float* __restrict__ w_ws,
        float* __restrict__ out) {
    int bs = blockIdx.x;
    int b  = bs >> 7;          // / S_
    float w = w_ws[bs];
    if (w == 0.0f) return;     // block-uniform, safe

    int t = threadIdx.x;       // 0..255, each owns 4 consecutive h (float4)
    int row = sent_head[bs];

    const float4* emb4 = reinterpret_cast<const float4*>(
        backbone + ((size_t)b * L_ + (size_t)row) * H_);
    float4 e = emb4[t];

    const float4* W4 = reinterpret_cast<const float4*>(W);
    float p[5];
#pragma unroll
    for (int j = 0; j < 5; ++j) {
        float4 wv = W4[j * (H_ / 4) + t];
        p[j] = e.x * wv.x + e.y * wv.y + e.z * wv.z + e.w * wv.w;
    }

    // wave-level reduce (width 64)
#pragma unroll
    for (int j = 0; j < 5; ++j) {
        float v = p[j];
        for (int off = 32; off > 0; off >>= 1)
            v += __shfl_down(v, off, 64);
        p[j] = v;
    }

    __shared__ float red[4][5];
    int wave = t >> 6, lane = t & 63;
    if (lane == 0) {
#pragma unroll
        for (int j = 0; j < 5; ++j) red[wave][j] = p[j];
    }
    __syncthreads();

    if (t < 5) {
        float tot = red[0][t] + red[1][t] + red[2][t] + red[3][t];
        atomicAdd(out + b * 5 + t, w * tot);
    }
}

extern "C" void kernel_launch(void* const* d_in, const int* in_sizes, int n_in,
                              void* d_out, int out_size, void* d_ws, size_t ws_size,
                              hipStream_t stream) {
    const float* backbone  = (const float*)d_in[0];
    // d_in[1] = attention_mask (unused by reference)
    const int*   par_head  = (const int*)d_in[2];
    const int*   par_tail  = (const int*)d_in[3];
    // d_in[4] = paragraph_attention_mask (unused)
    const int*   sent_head = (const int*)d_in[5];
    // d_in[6] = sentence_tail_idxs (unused), d_in[7] = sentence_attention_mask (unused)
    const float* W         = (const float*)d_in[8];
    const float* bias      = (const float*)d_in[9];

    float* out  = (float*)d_out;
    float* w_ws = (float*)d_ws;   // B_*S_ floats = 8 KB

    msh_weights<<<B_, S_, 0, stream>>>(par_head, par_tail, sent_head, bias, w_ws, out);
    msh_main<<<B_ * S_, 256, 0, stream>>>(backbone, sent_head, W, w_ws, out);
}

// Round 2
// 13.476 us; speedup vs baseline: 2.1980x; 2.1980x over previous
//
#include <hip/hip_runtime.h>

// MultiScaleHead: B=16, L=2048, H=1024, P=16, S=128
#define B_ 16
#define L_ 2048
#define H_ 1024
#define P_ 16
#define S_ 128

// Single fused kernel: one block per batch element, 1024 threads.
// out[b,j] = sum_s w[b,s] * dot(backbone[b, sent_head[b,s], :], W[j,:]) + bias[j]
// where w[b,s] = sum_p valid[p]*inside(p,s) / (par_cnt * sent_cnt[p])
__global__ void __launch_bounds__(1024) msh_fused(
        const float* __restrict__ backbone,
        const int* __restrict__ par_head,
        const int* __restrict__ par_tail,
        const int* __restrict__ sent_head,
        const float* __restrict__ W,
        const float* __restrict__ bias,
        float* __restrict__ out) {
    int b = blockIdx.x;
    int t = threadIdx.x;

    __shared__ int   sh[S_];
    __shared__ int   ph[P_], pt[P_];
    __shared__ float inv_scnt[P_];
    __shared__ int   validp[P_];
    __shared__ float invpar;
    __shared__ float wgt[S_];
    __shared__ float red[16][5];

    if (t < S_) sh[t] = sent_head[b * S_ + t];
    if (t >= S_ && t < S_ + P_) {
        int p = t - S_;
        ph[p] = par_head[b * P_ + p];
        pt[p] = par_tail[b * P_ + p];
    }
    __syncthreads();

    // Per-paragraph count + any-nonzero: wave w handles paragraph p=w.
    {
        int p = t >> 6, lane = t & 63;
        int h0 = ph[p], t0 = pt[p];
        int s1 = lane, s2 = lane + 64;
        int in1 = (h0 <= sh[s1]) && (sh[s1] <= t0);
        int in2 = (h0 <= sh[s2]) && (sh[s2] <= t0);
        int cnt = in1 + in2;
        int nz  = (in1 && sh[s1] != 0) || (in2 && sh[s2] != 0);
        for (int off = 32; off > 0; off >>= 1) {
            cnt += __shfl_down(cnt, off, 64);
            nz  |= __shfl_down(nz,  off, 64);
        }
        if (lane == 0) {
            int valid = ((t0 - h0) > 2) && nz;
            validp[p] = valid;
            inv_scnt[p] = valid ? 1.0f / (float)(cnt > 1 ? cnt : 1) : 0.0f;
        }
    }
    __syncthreads();
    if (t == 0) {
        int pc = 0;
        for (int p = 0; p < P_; ++p) pc += validp[p];
        invpar = 1.0f / (float)(pc > 1 ? pc : 1);
    }
    __syncthreads();
    if (t < S_) {
        int myh = sh[t];
        float w = 0.0f;
        for (int p = 0; p < P_; ++p)
            if (ph[p] <= myh && myh <= pt[p]) w += inv_scnt[p];
        wgt[t] = w * invpar;
    }
    __syncthreads();

    // Weighted row accumulation: 4 groups of 256 threads; group g takes
    // sentences s = g, g+4, ...; each thread owns one float4 of H.
    int grp = t >> 8, q = t & 255;
    const float4* bb4 = reinterpret_cast<const float4*>(
        backbone + (size_t)b * L_ * H_);
    float4 acc = make_float4(0.f, 0.f, 0.f, 0.f);
#pragma unroll 4
    for (int s = grp; s < S_; s += 4) {
        int row = sh[s];       // LDS broadcast (uniform within group)
        float w = wgt[s];
        float4 v = bb4[row * (H_ / 4) + q];
        acc.x += w * v.x; acc.y += w * v.y; acc.z += w * v.z; acc.w += w * v.w;
    }

    // 5 dot products vs W rows, then block reduction.
    const float4* W4 = reinterpret_cast<const float4*>(W);
    float pj[5];
#pragma unroll
    for (int j = 0; j < 5; ++j) {
        float4 wv = W4[j * (H_ / 4) + q];
        pj[j] = acc.x * wv.x + acc.y * wv.y + acc.z * wv.z + acc.w * wv.w;
    }
    int wave = t >> 6, lane = t & 63;
#pragma unroll
    for (int j = 0; j < 5; ++j) {
        float v = pj[j];
        for (int off = 32; off > 0; off >>= 1) v += __shfl_down(v, off, 64);
        pj[j] = v;
    }
    if (lane == 0) {
#pragma unroll
        for (int j = 0; j < 5; ++j) red[wave][j] = pj[j];
    }
    __syncthreads();

    if (t < 5) {
        float tot = 0.0f;
#pragma unroll
        for (int i = 0; i < 16; ++i) tot += red[i][t];
        out[b * 5 + t] = tot + bias[t];
    }
}

extern "C" void kernel_launch(void* const* d_in, const int* in_sizes, int n_in,
                              void* d_out, int out_size, void* d_ws, size_t ws_size,
                              hipStream_t stream) {
    const float* backbone  = (const float*)d_in[0];
    // d_in[1] = attention_mask (unused by reference)
    const int*   par_head  = (const int*)d_in[2];
    const int*   par_tail  = (const int*)d_in[3];
    // d_in[4] = paragraph_attention_mask (unused)
    const int*   sent_head = (const int*)d_in[5];
    // d_in[6] = sentence_tail_idxs (unused), d_in[7] = sentence_attention_mask (unused)
    const float* W         = (const float*)d_in[8];
    const float* bias      = (const float*)d_in[9];

    float* out = (float*)d_out;

    msh_fused<<<B_, 1024, 0, stream>>>(backbone, par_head, par_tail, sent_head,
                                       W, bias, out);
}